// Round 3
// baseline (1240.601 us; speedup 1.0000x reference)
//
#include <hip/hip_runtime.h>
#include <cstdint>
#include <cstddef>

#define Nn 102400
#define Ff 400
#define Ee 1638400
#define Kk 300
#define Bb 256
#define CAP 64

// ---------------- degree / norm ----------------
__global__ void deg_k(const int* __restrict__ ei, int* __restrict__ deg) {
    int e = blockIdx.x * 256 + threadIdx.x;
    if (e < Ee) atomicAdd(&deg[ei[Ee + e]], 1);
}

__global__ void dis_k(const int* __restrict__ deg, double* __restrict__ dis) {
    int v = blockIdx.x * 256 + threadIdx.x;
    if (v < Nn) dis[v] = 1.0 / sqrt((double)(deg[v] + 1));   // +1 self loop
}

__global__ void scat_k(const int* __restrict__ ei, int* __restrict__ fill,
                       int* __restrict__ csr) {
    int e = blockIdx.x * 256 + threadIdx.x;
    if (e >= Ee) return;
    int s = ei[e], d = ei[Ee + e];
    int p = atomicAdd(&fill[d], 1);
    if (p < CAP) csr[(size_t)d * CAP + p] = s;
}

// Deterministic row order (atomic fill order varies per call; fp64 makes the
// resulting summation-order noise ~1e-16, far below sort-flip scale).
__global__ __launch_bounds__(256) void sortrow_k(const int* __restrict__ deg,
                                                 int* __restrict__ csr) {
    int lane = threadIdx.x & 63;
    int v = blockIdx.x * 4 + (threadIdx.x >> 6);
    int dv = min(deg[v], CAP);
    int key = (lane < dv) ? csr[(size_t)v * CAP + lane] : 0x7FFFFFFF;
#pragma unroll
    for (int k = 2; k <= 64; k <<= 1) {
#pragma unroll
        for (int j = k >> 1; j; j >>= 1) {
            int other = __shfl_xor(key, j);
            bool up = ((lane & k) == 0);
            bool lower = ((lane & j) == 0);
            key = (lower == up) ? min(key, other) : max(key, other);
        }
    }
    if (lane < dv) csr[(size_t)v * CAP + lane] = key;
}

// ---------------- [M,400|64] @ [K,64] fp64-accumulate GEMM, BM=128, BK=16 ----
template <typename AT>
__global__ __launch_bounds__(256) void gemm_f64(const AT* __restrict__ A,
                                                const float* __restrict__ B,
                                                double* __restrict__ C, int K) {
    __shared__ double As[16][132];
    __shared__ double Bs[16][68];
    int tid = threadIdx.x;
    int m0 = blockIdx.x * 128;
    int tx = tid & 15, ty = tid >> 4;
    int arow = tid >> 1, acol = (tid & 1) * 8;
    int bk = tid >> 4, bn = (tid & 15) * 4;
    double acc[8][4] = {};
    for (int k0 = 0; k0 < K; k0 += 16) {
        double a[8];
        const AT* ap = A + (size_t)(m0 + arow) * K + k0 + acol;
        if constexpr (sizeof(AT) == 4) {
            float4 v0 = *(const float4*)(ap);
            float4 v1 = *(const float4*)(ap + 4);
            a[0] = v0.x; a[1] = v0.y; a[2] = v0.z; a[3] = v0.w;
            a[4] = v1.x; a[5] = v1.y; a[6] = v1.z; a[7] = v1.w;
        } else {
            double2 d0 = *(const double2*)(ap);
            double2 d1 = *(const double2*)(ap + 2);
            double2 d2 = *(const double2*)(ap + 4);
            double2 d3 = *(const double2*)(ap + 6);
            a[0] = d0.x; a[1] = d0.y; a[2] = d1.x; a[3] = d1.y;
            a[4] = d2.x; a[5] = d2.y; a[6] = d3.x; a[7] = d3.y;
        }
        float4 bv = *(const float4*)(B + (size_t)(k0 + bk) * 64 + bn);
        __syncthreads();
#pragma unroll
        for (int i = 0; i < 8; ++i) As[acol + i][arow] = a[i];
        Bs[bk][bn + 0] = bv.x; Bs[bk][bn + 1] = bv.y;
        Bs[bk][bn + 2] = bv.z; Bs[bk][bn + 3] = bv.w;
        __syncthreads();
#pragma unroll
        for (int kk = 0; kk < 16; ++kk) {
            double av[8], bvr[4];
#pragma unroll
            for (int i = 0; i < 8; ++i) av[i] = As[kk][ty * 8 + i];
#pragma unroll
            for (int j = 0; j < 4; ++j) bvr[j] = Bs[kk][tx * 4 + j];
#pragma unroll
            for (int i = 0; i < 8; ++i)
#pragma unroll
                for (int j = 0; j < 4; ++j) acc[i][j] += av[i] * bvr[j];
        }
    }
#pragma unroll
    for (int i = 0; i < 8; ++i) {
        double* cp = C + (size_t)(m0 + ty * 8 + i) * 64 + tx * 4;
        *(double2*)(cp)     = make_double2(acc[i][0], acc[i][1]);
        *(double2*)(cp + 2) = make_double2(acc[i][2], acc[i][3]);
    }
}

// ------- out = tanh(bias + dsv*(sum_u du*t[u] + dsv*t[v])), 64-wide fp64 -------
__global__ __launch_bounds__(256) void agg64_k(const double* __restrict__ t,
                                               const float* __restrict__ bias,
                                               const double* __restrict__ dis,
                                               const int* __restrict__ deg,
                                               const int* __restrict__ csr,
                                               double* __restrict__ out) {
    int lane = threadIdx.x & 63;
    int v = blockIdx.x * 4 + (threadIdx.x >> 6);
    int dv = min(deg[v], CAP);
    double dsv = dis[v];
    int idx = 0; double du = 0.0;
    if (lane < dv) { idx = csr[(size_t)v * CAP + lane]; du = dis[idx]; }
    double acc = 0.0;
    for (int j = 0; j < dv; ++j) {
        int u = __shfl(idx, j);
        double d = __shfl(du, j);
        acc += d * t[(size_t)u * 64 + lane];
    }
    acc += dsv * t[(size_t)v * 64 + lane];   // self-loop last (ref appends loops)
    out[(size_t)v * 64 + lane] = tanh((double)bias[lane] + dsv * acc);
}

// ---------------- layer 4: t4 = h3 @ W4  (wave per node, 64-dot) ----------------
__global__ __launch_bounds__(256) void trans4_k(const double* __restrict__ h3,
                                                const float* __restrict__ W4,
                                                double* __restrict__ t4) {
    int lane = threadIdx.x & 63;
    int v = blockIdx.x * 4 + (threadIdx.x >> 6);
    double x = h3[(size_t)v * 64 + lane] * (double)W4[lane];
#pragma unroll
    for (int o = 32; o > 0; o >>= 1) x += __shfl_xor(x, o);
    if (lane == 0) t4[v] = x;
}

__global__ void agg1_k(const double* __restrict__ t4, const double* __restrict__ dis,
                       const int* __restrict__ deg, const int* __restrict__ csr,
                       const float* __restrict__ b4, double* __restrict__ h4) {
    int v = blockIdx.x * 256 + threadIdx.x;
    if (v >= Nn) return;
    int dv = min(deg[v], CAP);
    double dsv = dis[v];
    double acc = 0.0;
    const int* row = csr + (size_t)v * CAP;
    for (int j = 0; j < dv; ++j) { int u = row[j]; acc += dis[u] * t4[u]; }
    acc += dsv * t4[v];
    h4[v] = tanh((double)b4[0] + dsv * acc);
}

// ------- per-graph stable top-300 sort on fp64 keys (bitonic, 512 in LDS) -------
__global__ __launch_bounds__(512) void sort_k(const double* __restrict__ h4,
                                              int* __restrict__ order) {
    __shared__ unsigned long long kv[512];
    __shared__ int ki[512];
    int tid = threadIdx.x, g = blockIdx.x;
    unsigned long long key = ~0ull;
    if (tid < 400) {
        unsigned long long u = (unsigned long long)__double_as_longlong(h4[g * 400 + tid]);
        u = (u & 0x8000000000000000ull) ? ~u : (u | 0x8000000000000000ull); // asc map
        key = ~u;                                                           // descending
    }
    kv[tid] = key; ki[tid] = tid;
    __syncthreads();
    for (int size = 2; size <= 512; size <<= 1) {
        for (int stride = size >> 1; stride > 0; stride >>= 1) {
            int p = tid ^ stride;
            if (p > tid) {
                bool asc = ((tid & size) == 0);
                unsigned long long a = kv[tid], b = kv[p];
                int ia = ki[tid], ib = ki[p];
                bool gt = (a > b) || (a == b && ia > ib);   // stable tie-break
                if (gt == asc) { kv[tid] = b; kv[p] = a; ki[tid] = ib; ki[p] = ia; }
            }
            __syncthreads();
        }
    }
    if (tid < Kk) order[g * Kk + tid] = ki[tid];
}

// ---------------- conv1: z1[b,c,k] = relu(cb1[c] + sum_d feat[n,d]*cw1[c,d]) ----
__global__ __launch_bounds__(128) void conv1_k(const double* __restrict__ h1,
                                               const double* __restrict__ h2,
                                               const double* __restrict__ h3,
                                               const double* __restrict__ h4,
                                               const int* __restrict__ order,
                                               const float* __restrict__ cw1,
                                               const float* __restrict__ cb1,
                                               double* __restrict__ z1) {
    __shared__ double wt[193 * 16];   // transposed [d][c]
    int tid = threadIdx.x, b = blockIdx.y;
    for (int i = tid; i < 193 * 16; i += 128) {
        int c = i / 193, d = i % 193;
        wt[d * 16 + c] = (double)cw1[i];
    }
    __syncthreads();
    int kpos = blockIdx.x * 128 + tid;
    if (kpos >= Kk) return;
    int n = b * 400 + order[b * Kk + kpos];
    double acc[16];
#pragma unroll
    for (int c = 0; c < 16; ++c) acc[c] = (double)cb1[c];
    const double* bases[3] = {h1 + (size_t)n * 64, h2 + (size_t)n * 64, h3 + (size_t)n * 64};
    for (int r = 0; r < 3; ++r) {
        const double* p = bases[r];
        for (int d = 0; d < 64; ++d) {
            double xv = p[d];
            const double* wp = &wt[((size_t)r * 64 + d) * 16];
#pragma unroll
            for (int c = 0; c < 16; ++c) acc[c] += xv * wp[c];
        }
    }
    double xl = h4[n];
    {
        const double* wp = &wt[192 * 16];
#pragma unroll
        for (int c = 0; c < 16; ++c) acc[c] += xl * wp[c];
    }
#pragma unroll
    for (int c = 0; c < 16; ++c)
        z1[((size_t)b * 16 + c) * 300 + kpos] = fmax(acc[c], 0.0);
}

__global__ void maxpool_k(const double* __restrict__ z1, double* __restrict__ z2) {
    int i = blockIdx.x * 256 + threadIdx.x;   // B*16*150
    if (i >= Bb * 16 * 150) return;
    int j = i % 150, bc = i / 150;
    z2[i] = fmax(z1[(size_t)bc * 300 + 2 * j], z1[(size_t)bc * 300 + 2 * j + 1]);
}

// ---------------- conv2: 16->32 channels, k=5, then relu ----------------
__global__ __launch_bounds__(256) void conv2_k(const double* __restrict__ z2,
                                               const float* __restrict__ cw2,
                                               const float* __restrict__ cb2,
                                               double* __restrict__ z3) {
    __shared__ double lz[16 * 150];
    __shared__ double lw[32 * 16 * 5];
    int b = blockIdx.x, tid = threadIdx.x;
    for (int i = tid; i < 2400; i += 256) lz[i] = z2[(size_t)b * 2400 + i];
    for (int i = tid; i < 2560; i += 256) lw[i] = (double)cw2[i];
    __syncthreads();
    for (int o = tid; o < 4672; o += 256) {
        int co = o / 146, j = o % 146;
        double acc = (double)cb2[co];
#pragma unroll
        for (int ci = 0; ci < 16; ++ci)
#pragma unroll
            for (int tt = 0; tt < 5; ++tt)
                acc += lz[ci * 150 + j + tt] * lw[co * 80 + ci * 5 + tt];
        z3[(size_t)b * 4672 + o] = fmax(acc, 0.0);
    }
}

// ---------------- MLP: relu(z3@mw1+mb1)@mw2+mb2 ----------------
__global__ __launch_bounds__(256) void mlp_k(const double* __restrict__ z3,
                                             const float* __restrict__ mw1,
                                             const float* __restrict__ mb1,
                                             const float* __restrict__ mw2,
                                             const float* __restrict__ mb2,
                                             float* __restrict__ out) {
    __shared__ double lz[4672];
    __shared__ double red[256];
    __shared__ double s4[32];
    int b = blockIdx.x, tid = threadIdx.x;
    for (int i = tid; i < 4672; i += 256) lz[i] = z3[(size_t)b * 4672 + i];
    __syncthreads();
    int o = tid & 31, part = tid >> 5;   // 8 parts x 584
    double acc = 0.0;
    for (int i = part * 584; i < (part + 1) * 584; ++i)
        acc += lz[i] * (double)mw1[(size_t)i * 32 + o];
    red[tid] = acc;
    __syncthreads();
    if (tid < 32) {
        double s = 0.0;
#pragma unroll
        for (int p = 0; p < 8; ++p) s += red[p * 32 + tid];
        s4[tid] = fmax(s + (double)mb1[tid], 0.0);
    }
    __syncthreads();
    if (tid < 2) {
        double s = (double)mb2[tid];
#pragma unroll
        for (int j = 0; j < 32; ++j) s += s4[j] * (double)mw2[j * 2 + tid];
        out[b * 2 + tid] = (float)s;
    }
}

extern "C" void kernel_launch(void* const* d_in, const int* in_sizes, int n_in,
                              void* d_out, int out_size, void* d_ws, size_t ws_size,
                              hipStream_t stream) {
    const float* x   = (const float*)d_in[0];
    const int*   ei  = (const int*)d_in[1];
    const float* W1  = (const float*)d_in[2];  const float* b1  = (const float*)d_in[3];
    const float* W2  = (const float*)d_in[4];  const float* b2  = (const float*)d_in[5];
    const float* W3  = (const float*)d_in[6];  const float* b3  = (const float*)d_in[7];
    const float* W4  = (const float*)d_in[8];  const float* b4  = (const float*)d_in[9];
    const float* cw1 = (const float*)d_in[10]; const float* cb1 = (const float*)d_in[11];
    const float* cw2 = (const float*)d_in[12]; const float* cb2 = (const float*)d_in[13];
    const float* mw1 = (const float*)d_in[14]; const float* mb1 = (const float*)d_in[15];
    const float* mw2 = (const float*)d_in[16]; const float* mb2 = (const float*)d_in[17];
    float* out = (float*)d_out;

    const size_t N64 = (size_t)Nn * 64;
    double* t   = (double*)d_ws;          // [N,64] transform scratch (fp64)
    double* h1  = t + N64;
    double* h2  = h1 + N64;
    double* h3  = h2 + N64;
    double* t4  = h3 + N64;               // [N]
    double* h4  = t4 + Nn;                // [N]
    double* dis = h4 + Nn;                // [N]
    int*   deg  = (int*)(dis + Nn);
    int*   fill = deg + Nn;
    int*   csr  = fill + Nn;              // [N,CAP]
    int*   order = csr + (size_t)Nn * CAP;
    // z buffers alias t (free after aggregation stages)
    double* z1 = t;                        // [B,16,300]
    double* z2 = z1 + (size_t)Bb * 16 * 300;
    double* z3 = z2 + (size_t)Bb * 16 * 150;

    hipMemsetAsync(deg, 0, sizeof(int) * (size_t)Nn * 2, stream);  // deg + fill

    deg_k <<<Ee / 256, 256, 0, stream>>>(ei, deg);
    dis_k <<<Nn / 256, 256, 0, stream>>>(deg, dis);
    scat_k<<<Ee / 256, 256, 0, stream>>>(ei, fill, csr);
    sortrow_k<<<Nn / 4, 256, 0, stream>>>(deg, csr);   // deterministic row order

    gemm_f64<float> <<<Nn / 128, 256, 0, stream>>>(x, W1, t, Ff);
    agg64_k <<<Nn / 4, 256, 0, stream>>>(t, b1, dis, deg, csr, h1);
    gemm_f64<double><<<Nn / 128, 256, 0, stream>>>(h1, W2, t, 64);
    agg64_k <<<Nn / 4, 256, 0, stream>>>(t, b2, dis, deg, csr, h2);
    gemm_f64<double><<<Nn / 128, 256, 0, stream>>>(h2, W3, t, 64);
    agg64_k <<<Nn / 4, 256, 0, stream>>>(t, b3, dis, deg, csr, h3);

    trans4_k<<<Nn / 4, 256, 0, stream>>>(h3, W4, t4);
    agg1_k  <<<Nn / 256, 256, 0, stream>>>(t4, dis, deg, csr, b4, h4);

    sort_k<<<Bb, 512, 0, stream>>>(h4, order);
    conv1_k<<<dim3(3, Bb), 128, 0, stream>>>(h1, h2, h3, h4, order, cw1, cb1, z1);
    maxpool_k<<<Bb * 16 * 150 / 256, 256, 0, stream>>>(z1, z2);
    conv2_k<<<Bb, 256, 0, stream>>>(z2, cw2, cb2, z3);
    mlp_k  <<<Bb, 256, 0, stream>>>(z3, mw1, mb1, mw2, mb2, out);
}